// Round 10
// baseline (3096.461 us; speedup 1.0000x reference)
//
#include <hip/hip_runtime.h>
#include <hip/hip_bf16.h>

// Sizes (fixed by the problem)
#define BATCH 4
#define NPTS  8192
#define NSAMP 2048
#define NK    16
#define CFEAT 64
#define CG    67      // 3 + 64
#define CO1   128
#define CCAT  192     // 64 + 128
#define CO2   128

#define DEV __device__ __forceinline__

typedef float f32x2 __attribute__((ext_vector_type(2)));

// --- exact-rounding helpers (block fp-contraction; match reference numerics) ---
DEV float n3(float x, float y, float z) {
    return __fadd_rn(__fadd_rn(__fmul_rn(x, x), __fmul_rn(y, y)), __fmul_rn(z, z));
}
DEV float dot3(float ax, float ay, float az, float bx, float by, float bz) {
    return __fmaf_rn(az, bz, __fmaf_rn(ay, by, __fmul_rn(ax, bx)));
}
DEV float sqd_expand(float an, float bn, float d) {
    return __fsub_rn(__fadd_rn(an, bn), __fmul_rn(2.0f, d));
}

// --- packed f32 ops (VOP3P): IEEE rn per element, identical to scalar VALU ---
DEV f32x2 pk_add(f32x2 a, f32x2 b) {
    f32x2 d;
    asm("v_pk_add_f32 %0, %1, %2" : "=v"(d) : "v"(a), "v"(b));
    return d;
}
DEV f32x2 pk_mul(f32x2 a, f32x2 b) {
    f32x2 d;
    asm("v_pk_mul_f32 %0, %1, %2" : "=v"(d) : "v"(a), "v"(b));
    return d;
}

// one DPP f32 max step: x = max(x, lanes-moved(x))
#define DPPMAX(x, ctrl)                                                        \
    x = fmaxf(x, __int_as_float(__builtin_amdgcn_update_dpp(                   \
            __float_as_int(x), __float_as_int(x), (ctrl), 0xF, 0xF, false)))

// one DPP u32 max step
#define DPPMAXU(x, ctrl)                                                       \
    do {                                                                       \
        unsigned _o = (unsigned)__builtin_amdgcn_update_dpp(                   \
            (int)(x), (int)(x), (ctrl), 0xF, 0xF, false);                      \
        x = (x > _o) ? x : _o;                                                 \
    } while (0)

// u64 DPP row_shr max step (ctrl is a template constant)
template <int CTRL>
DEV void dpp_shr_max64(unsigned& hi, unsigned& lo) {
    unsigned nh = (unsigned)__builtin_amdgcn_update_dpp((int)hi, (int)hi, CTRL, 0xF, 0xF, false);
    unsigned nl = (unsigned)__builtin_amdgcn_update_dpp((int)lo, (int)lo, CTRL, 0xF, 0xF, false);
    unsigned long long a = ((unsigned long long)hi << 32) | lo;
    unsigned long long n = ((unsigned long long)nh << 32) | nl;
    if (n > a) { hi = nh; lo = nl; }
}

DEV float rlane(float v, int l) {
    return __int_as_float(__builtin_amdgcn_readlane(__float_as_int(v), l));
}

// octant-major + local Morton cell key (512 bins): wave-sized sorted chunks
// (512 pts) span ~0.5 x 0.5 x 0.25 boxes -> wave bounding rad ~0.375.
DEV int mortkey(float x, float y, float z) {
    int ix = min(7, (int)(x * 8.0f));
    int iy = min(7, (int)(y * 8.0f));
    int iz = min(7, (int)(z * 8.0f));
    int oct = ((iz >> 2) << 2) | ((iy >> 2) << 1) | (ix >> 2);
    int m = (ix & 1) | ((iy & 1) << 1) | ((iz & 1) << 2)
          | (((ix >> 1) & 1) << 3) | (((iy >> 1) & 1) << 4) | (((iz >> 1) & 1) << 5);
    return (oct << 6) | m;
}

// ============================================================================
// K0: transpose features (B,64,8192) -> featT (B,8192,64)
// ============================================================================
__global__ __launch_bounds__(256) void transpose_kernel(const float* __restrict__ F,
                                                        float* __restrict__ T) {
    __shared__ float tile[64][65];
    const int b = blockIdx.y;
    const int n0 = blockIdx.x * 64;
    const int tx = threadIdx.x & 63, ty = threadIdx.x >> 6;
    const float* Fb = F + (size_t)b * CFEAT * NPTS;
    float* Tb = T + (size_t)b * NPTS * CFEAT;
#pragma unroll
    for (int i = 0; i < 16; i++) {
        int c = ty + i * 4;
        tile[c][tx] = Fb[(size_t)c * NPTS + n0 + tx];
    }
    __syncthreads();
#pragma unroll
    for (int i = 0; i < 16; i++) {
        int r = ty + i * 4;
        Tb[(size_t)(n0 + r) * CFEAT + tx] = tile[tx][r];
    }
}

// ============================================================================
// K1: FPS with wave-uniform spatial skip at Morton-chunk granularity.
// 1024 threads = 16 waves, 8 sorted pts/lane (pairs for v_pk). Coords stay in
// ORIGINAL order in LDS (sxy/szl); sidx maps sorted slot -> orig id, so the
// winner's orig id serves BOTH the first-occurrence tie-break and the
// centroid fetch. Per iteration (ONE barrier):
//   wave-uniform skip: |c-ref|^2 >= (rad + sb)^2 with conservative margins
//   (sb = sqrt(wave max)*1.0001+1e-6). Skipped wave's cached winner stays
//   exact (no owned dist changed). Active wave: pk update (exact numpy
//   rounding), 8-pt max tree, min-orig-id tie scan, f32 DPP wave max, u32
//   DPP ~min-pid tie resolve, pack u64 (bits(v)<<32 | ~minpid).
//   lane0 -> wred[parity][wv]; barrier; 16-winner u64 DPP reduce (4 row_shr
//   steps, lanes 0..15); centroid via 2 orig-order broadcast reads.
// All reductions are permutation-invariant (max of u64 packs), so the
// nondeterministic atomic scatter cannot change the output.
// ============================================================================
__global__ __launch_bounds__(1024, 4) void fps_kernel(const float* __restrict__ xyz,
                                                      float* __restrict__ new_xyz) {
    const int b = blockIdx.x;
    const int t = threadIdx.x;               // 0..1023
    const int lane = t & 63, wv = t >> 6;    // 16 waves
    const float* X = xyz + (size_t)b * NPTS * 3;

    __shared__ f32x2 sxy[NPTS];              // 64 KiB orig-order (x,y)
    __shared__ float szl[NPTS];              // 32 KiB orig-order z
    __shared__ unsigned short sidx[NPTS];    // 16 KiB sorted -> orig id
    __shared__ unsigned int cnt_off[512];    // 2 KiB
    __shared__ unsigned long long wred[2][16];

    // ---- load 8 original points (orig ids 8t..8t+7) -> LDS orig order ----
    {
        const float4* X4 = (const float4*)X;
        float4 f0 = X4[t*6+0], f1 = X4[t*6+1], f2 = X4[t*6+2];
        float4 f3 = X4[t*6+3], f4 = X4[t*6+4], f5 = X4[t*6+5];
        float ox[8], oy[8], oz[8];
        ox[0]=f0.x; oy[0]=f0.y; oz[0]=f0.z;
        ox[1]=f0.w; oy[1]=f1.x; oz[1]=f1.y;
        ox[2]=f1.z; oy[2]=f1.w; oz[2]=f2.x;
        ox[3]=f2.y; oy[3]=f2.z; oz[3]=f2.w;
        ox[4]=f3.x; oy[4]=f3.y; oz[4]=f3.z;
        ox[5]=f3.w; oy[5]=f4.x; oz[5]=f4.y;
        ox[6]=f4.z; oy[6]=f4.w; oz[6]=f5.x;
        ox[7]=f5.y; oy[7]=f5.z; oz[7]=f5.w;
#pragma unroll
        for (int j = 0; j < 8; j++) {
            int p = t * 8 + j;
            sxy[p].x = ox[j]; sxy[p].y = oy[j]; szl[p] = oz[j];
        }
        if (t < 512) cnt_off[t] = 0;
        __syncthreads();
        // histogram
#pragma unroll
        for (int j = 0; j < 8; j++)
            atomicAdd(&cnt_off[mortkey(ox[j], oy[j], oz[j])], 1u);
        __syncthreads();
        // exclusive scan over 512 bins (wave 0, 8 bins/lane)
        if (t < 64) {
            unsigned h[8], lsum = 0;
#pragma unroll
            for (int k = 0; k < 8; k++) { h[k] = cnt_off[t * 8 + k]; lsum += h[k]; }
            unsigned run = lsum;
#pragma unroll
            for (int d = 1; d < 64; d <<= 1) {
                unsigned o = __shfl_up(run, d);
                if (lane >= d) run += o;
            }
            unsigned acc = run - lsum;
#pragma unroll
            for (int k = 0; k < 8; k++) { cnt_off[t * 8 + k] = acc; acc += h[k]; }
        }
        __syncthreads();
        // scatter: sorted slot -> orig id
#pragma unroll
        for (int j = 0; j < 8; j++) {
            int key = mortkey(ox[j], oy[j], oz[j]);
            unsigned pos = atomicAdd(&cnt_off[key], 1u);
            sidx[pos] = (unsigned short)(t * 8 + j);
        }
    }
    __syncthreads();

    // ---- gather sorted ownership (8 pts as 4 pairs) + orig ids ----
    f32x2 px[4], py[4], pz[4], dd[4];
    int pid[8];
#pragma unroll
    for (int j = 0; j < 8; j++) {
        int p = sidx[t * 8 + j];
        pid[j] = p;
        f32x2 xy = sxy[p];
        float z = szl[p];
        if (j & 1) { px[j >> 1].y = xy.x; py[j >> 1].y = xy.y; pz[j >> 1].y = z; }
        else       { px[j >> 1].x = xy.x; py[j >> 1].x = xy.y; pz[j >> 1].x = z; }
    }
#pragma unroll
    for (int j = 0; j < 4; j++) { dd[j].x = 1e10f; dd[j].y = 1e10f; }

    // ---- wave bounding sphere (bbox butterfly over the wave's 512 pts) ----
    float mnx = 1e30f, mxx = -1e30f, mny = 1e30f, mxy = -1e30f, mnz = 1e30f, mxz = -1e30f;
#pragma unroll
    for (int j = 0; j < 4; j++) {
        mnx = fminf(mnx, fminf(px[j].x, px[j].y)); mxx = fmaxf(mxx, fmaxf(px[j].x, px[j].y));
        mny = fminf(mny, fminf(py[j].x, py[j].y)); mxy = fmaxf(mxy, fmaxf(py[j].x, py[j].y));
        mnz = fminf(mnz, fminf(pz[j].x, pz[j].y)); mxz = fmaxf(mxz, fmaxf(pz[j].x, pz[j].y));
    }
#pragma unroll
    for (int off = 32; off > 0; off >>= 1) {
        mnx = fminf(mnx, __shfl_xor(mnx, off)); mxx = fmaxf(mxx, __shfl_xor(mxx, off));
        mny = fminf(mny, __shfl_xor(mny, off)); mxy = fmaxf(mxy, __shfl_xor(mxy, off));
        mnz = fminf(mnz, __shfl_xor(mnz, off)); mxz = fmaxf(mxz, __shfl_xor(mxz, off));
    }
    const float rx = 0.5f * (mnx + mxx), ry = 0.5f * (mny + mxy), rz = 0.5f * (mnz + mxz);
    float r2m = 0.0f;
#pragma unroll
    for (int j = 0; j < 4; j++) {
        float ax = px[j].x - rx, ay = py[j].x - ry, az = pz[j].x - rz;
        float bx2 = px[j].y - rx, by2 = py[j].y - ry, bz2 = pz[j].y - rz;
        r2m = fmaxf(r2m, ax * ax + ay * ay + az * az);
        r2m = fmaxf(r2m, bx2 * bx2 + by2 * by2 + bz2 * bz2);
    }
#pragma unroll
    for (int off = 32; off > 0; off >>= 1)
        r2m = fmaxf(r2m, __shfl_xor(r2m, off));
    const float rad = sqrtf(r2m) * 1.0001f + 1e-6f;   // wave-uniform

    f32x2 c0 = sxy[0];
    float cx = c0.x, cy = c0.y, cz = szl[0];          // first sampled index 0
    if (t == 0) {
        size_t o = (size_t)b * NSAMP * 3;
        new_xyz[o + 0] = cx; new_xyz[o + 1] = cy; new_xyz[o + 2] = cz;
    }

    unsigned long long wpack = 0;      // cached wave winner (set at s=1)
    float sb = 1e19f;                  // sqrt(wave max)+margin; huge -> s=1 active

    int par = 0;
    for (int s = 1; s < NSAMP; s++) {
        // ---- wave-uniform skip test (identical on all lanes -> execz) ----
        float ddx = cx - rx, ddy = cy - ry, ddz = cz - rz;
        float dc2 = ddx * ddx + ddy * ddy + ddz * ddz;
        float thr = rad + sb;
        if (dc2 < thr * thr) {
            // packed update: d = ((dx*dx + dy*dy) + dz*dz); x-c == x+(-c)
            const float ncx = -cx, ncy = -cy, ncz = -cz;
            const f32x2 vcx = {ncx, ncx}, vcy = {ncy, ncy}, vcz = {ncz, ncz};
#pragma unroll
            for (int j = 0; j < 4; j++) {
                f32x2 dx = pk_add(px[j], vcx);
                f32x2 dy = pk_add(py[j], vcy);
                f32x2 dz = pk_add(pz[j], vcz);
                f32x2 d = pk_add(pk_add(pk_mul(dx, dx), pk_mul(dy, dy)), pk_mul(dz, dz));
                dd[j].x = fminf(dd[j].x, d.x);
                dd[j].y = fminf(dd[j].y, d.y);
            }
            // per-lane max (tree over 8)
            float m0 = fmaxf(dd[0].x, dd[0].y), m1 = fmaxf(dd[1].x, dd[1].y);
            float m2 = fmaxf(dd[2].x, dd[2].y), m3 = fmaxf(dd[3].x, dd[3].y);
            float bv = fmaxf(fmaxf(m0, m1), fmaxf(m2, m3));
            // min orig id among owned ties (exact first-occurrence)
            int nb = 0x7fffffff;
#pragma unroll
            for (int j = 0; j < 8; j++) {
                float dj = (j & 1) ? dd[j >> 1].y : dd[j >> 1].x;
                if (dj == bv) nb = min(nb, pid[j]);
            }
            // wave f32 DPP max
            float wm = bv;
            DPPMAX(wm, 0x111); DPPMAX(wm, 0x112); DPPMAX(wm, 0x114);
            DPPMAX(wm, 0x118); DPPMAX(wm, 0x142); DPPMAX(wm, 0x143);
            const float wmax = rlane(wm, 63);
            // min orig id among tie lanes: u32 DPP max of (~nb or 0)
            unsigned tv = (bv == wmax) ? (unsigned)(~nb) : 0u;
            DPPMAXU(tv, 0x111); DPPMAXU(tv, 0x112); DPPMAXU(tv, 0x114);
            DPPMAXU(tv, 0x118); DPPMAXU(tv, 0x142); DPPMAXU(tv, 0x143);
            const unsigned tmax = (unsigned)__builtin_amdgcn_readlane((int)tv, 63);
            wpack = ((unsigned long long)__float_as_uint(wmax) << 32) | tmax;
            sb = sqrtf(wmax) * 1.0001f + 1e-6f;
        }
        if (lane == 0) wred[par][wv] = wpack;
        __syncthreads();                       // the ONLY barrier per iter

        // ---- cross-wave reduce: 16 winners via 4-step u64 DPP row_shr ----
        unsigned long long v = wred[par][lane & 15];
        unsigned hi = (unsigned)(v >> 32), lo = (unsigned)v;
        dpp_shr_max64<0x111>(hi, lo);
        dpp_shr_max64<0x112>(hi, lo);
        dpp_shr_max64<0x114>(hi, lo);
        dpp_shr_max64<0x118>(hi, lo);          // lane15 = max of lanes 0..15
        const int idx = ~__builtin_amdgcn_readlane((int)lo, 15);

        f32x2 cxy = sxy[idx];                  // orig-order broadcast reads
        cz = szl[idx];
        cx = cxy.x; cy = cxy.y;
        if (t == 0) {
            size_t o = ((size_t)b * NSAMP + s) * 3;
            new_xyz[o + 0] = cx; new_xyz[o + 1] = cy; new_xyz[o + 2] = cz;
        }
        par ^= 1;
    }
}

// ============================================================================
// K2: ball query. One wave per query; first 16 within r^2=0.04, pad w/ first.
// ============================================================================
__global__ __launch_bounds__(256) void ballq_kernel(const float* __restrict__ xyz,
                                                    const float* __restrict__ new_xyz,
                                                    int* __restrict__ nidx) {
    const int wv = threadIdx.x >> 6, lane = threadIdx.x & 63;
    const int q = blockIdx.x * 4 + wv;
    const int b = q >> 11;
    const float* X = xyz + (size_t)b * NPTS * 3;
    const float* Q = new_xyz + (size_t)q * 3;
    const float qx = Q[0], qy = Q[1], qz = Q[2];
    const float an = n3(qx, qy, qz);

    __shared__ int nb[4][NK];
    int cnt = 0;
    for (int base = 0; base < NPTS && cnt < NK; base += 64) {
        int p = base + lane;
        float x = X[p * 3 + 0], y = X[p * 3 + 1], z = X[p * 3 + 2];
        float bn = n3(x, y, z);
        float dt = dot3(qx, qy, qz, x, y, z);
        float sq = sqd_expand(an, bn, dt);
        bool in = (sq <= 0.04f);
        unsigned long long m = __ballot(in);
        if (in) {
            int pos = cnt + (int)__popcll(m & ((1ull << lane) - 1ull));
            if (pos < NK) nb[wv][pos] = p;
        }
        cnt += (int)__popcll(m);
    }
    __syncthreads();
    if (lane < NK) {
        int c = cnt < NK ? cnt : NK;
        int v = (lane < c) ? nb[wv][lane] : nb[wv][0];
        nidx[(size_t)q * NK + lane] = v;
    }
}

// ============================================================================
// K3: grouping + W1 + relu + max-over-k -> subxT (B,2048,128)
// ============================================================================
__global__ __launch_bounds__(256) void group_mlp_kernel(const float* __restrict__ xyz,
                                                        const float* __restrict__ featT,
                                                        const float* __restrict__ new_xyz,
                                                        const int* __restrict__ nidx,
                                                        const float* __restrict__ W1,
                                                        float* __restrict__ subxT) {
    __shared__ f32x2 w1t2[CG][64];
    for (int i = threadIdx.x; i < CG * 64; i += 256) {
        int d = i >> 6, o = i & 63;
        w1t2[d][o].x = W1[(size_t)o * CG + d];
        w1t2[d][o].y = W1[(size_t)(o + 64) * CG + d];
    }
    __syncthreads();
    const int lane = threadIdx.x & 63, wv = threadIdx.x >> 6;

    for (int q = blockIdx.x * 4 + wv; q < BATCH * NSAMP; q += gridDim.x * 4) {
        const int b = q >> 11;
        const float* Q = new_xyz + (size_t)q * 3;
        const float qx = Q[0], qy = Q[1], qz = Q[2];
        const int* NB = nidx + (size_t)q * NK;
        float m0 = 0.0f, m1 = 0.0f;
#pragma unroll 1
        for (int k = 0; k < NK; k += 2) {
            const int n0 = NB[k], n1 = NB[k + 1];
            const float* P0 = xyz + ((size_t)b * NPTS + n0) * 3;
            const float* P1 = xyz + ((size_t)b * NPTS + n1) * 3;
            float rx0 = P0[0] - qx, ry0 = P0[1] - qy, rz0 = P0[2] - qz;
            float rx1 = P1[0] - qx, ry1 = P1[1] - qy, rz1 = P1[2] - qz;
            float fv0 = featT[((size_t)b * NPTS + n0) * CFEAT + lane];
            float fv1 = featT[((size_t)b * NPTS + n1) * CFEAT + lane];
            f32x2 w0 = w1t2[0][lane], w1 = w1t2[1][lane], w2 = w1t2[2][lane];
            float a0 = fmaf(w0.x, rx0, fmaf(w1.x, ry0, w2.x * rz0));
            float a1 = fmaf(w0.y, rx0, fmaf(w1.y, ry0, w2.y * rz0));
            float c0 = fmaf(w0.x, rx1, fmaf(w1.x, ry1, w2.x * rz1));
            float c1 = fmaf(w0.y, rx1, fmaf(w1.y, ry1, w2.y * rz1));
#pragma unroll
            for (int c = 0; c < 64; c++) {
                f32x2 w = w1t2[3 + c][lane];
                float g0 = rlane(fv0, c);
                float g1 = rlane(fv1, c);
                a0 = fmaf(w.x, g0, a0);
                a1 = fmaf(w.y, g0, a1);
                c0 = fmaf(w.x, g1, c0);
                c1 = fmaf(w.y, g1, c1);
            }
            m0 = fmaxf(m0, fmaxf(a0, c0));
            m1 = fmaxf(m1, fmaxf(a1, c1));
        }
        subxT[(size_t)q * CO1 + lane] = m0;
        subxT[(size_t)q * CO1 + 64 + lane] = m1;
    }
}

// ============================================================================
// K4: 3-NN interp + concat + W2 + relu -> out. 512 threads (8 waves, 2/SIMD)
// to hide the LDS-read chains; one wave per output point otherwise unchanged.
// ============================================================================
DEV void ins3(float dd, int jj,
              float& d0, int& i0, float& d1, int& i1, float& d2, int& i2) {
    bool c2 = (dd < d2) || (dd == d2 && jj < i2);
    if (c2) { d2 = dd; i2 = jj; }
    bool c1 = (d2 < d1) || (d2 == d1 && i2 < i1);
    if (c1) { float tv = d1; int ti = i1; d1 = d2; i1 = i2; d2 = tv; i2 = ti; }
    bool c0 = (d1 < d0) || (d1 == d0 && i1 < i0);
    if (c0) { float tv = d0; int ti = i0; d0 = d1; i0 = i1; d1 = tv; i1 = ti; }
}

__global__ __launch_bounds__(512) void interp_w2_kernel(const float* __restrict__ xyz,
                                                        const float* __restrict__ new_xyz,
                                                        const float* __restrict__ featT,
                                                        const float* __restrict__ subxT,
                                                        const float* __restrict__ W2,
                                                        float* __restrict__ out) {
    __shared__ f32x2 w2t2[CCAT][64];  // 96 KiB
    for (int i = threadIdx.x; i < CCAT * 64; i += 512) {
        int d = i >> 6, o = i & 63;
        w2t2[d][o].x = W2[(size_t)o * CCAT + d];
        w2t2[d][o].y = W2[(size_t)(o + 64) * CCAT + d];
    }
    __syncthreads();
    const int lane = threadIdx.x & 63, wv = threadIdx.x >> 6;   // 8 waves

    for (int q = blockIdx.x * 8 + wv; q < BATCH * NPTS; q += gridDim.x * 8) {
        const int b = q >> 13, n = q & (NPTS - 1);
        const float* P = xyz + (size_t)q * 3;
        const float qx = P[0], qy = P[1], qz = P[2];
        const float an = n3(qx, qy, qz);

        float d0 = 1e30f, d1 = 1e30f, d2 = 1e30f;
        int i0 = 0x7fffffff, i1 = 0x7fffffff, i2 = 0x7fffffff;
        for (int j = lane; j < NSAMP; j += 64) {
            const float* C = new_xyz + ((size_t)b * NSAMP + j) * 3;
            float x = C[0], y = C[1], z = C[2];
            float bn = n3(x, y, z);
            float dt = dot3(qx, qy, qz, x, y, z);
            float dd = sqd_expand(an, bn, dt);
            ins3(dd, j, d0, i0, d1, i1, d2, i2);
        }
#pragma unroll
        for (int off = 32; off > 0; off >>= 1) {
            float e0 = __shfl_xor(d0, off); int f0 = __shfl_xor(i0, off);
            float e1 = __shfl_xor(d1, off); int f1 = __shfl_xor(i1, off);
            float e2 = __shfl_xor(d2, off); int f2 = __shfl_xor(i2, off);
            ins3(e0, f0, d0, i0, d1, i1, d2, i2);
            ins3(e1, f1, d0, i0, d1, i1, d2, i2);
            ins3(e2, f2, d0, i0, d1, i1, d2, i2);
        }
        float w0 = 1.0f / (d0 + 1e-8f);
        float w1 = 1.0f / (d1 + 1e-8f);
        float w2 = 1.0f / (d2 + 1e-8f);
        float sw = (w0 + w1) + w2;
        w0 /= sw; w1 /= sw; w2 /= sw;

        const float* S = subxT + (size_t)b * NSAMP * CO1;
        float L0 = S[(size_t)i0 * CO1 + lane] * w0
                 + S[(size_t)i1 * CO1 + lane] * w1
                 + S[(size_t)i2 * CO1 + lane] * w2;
        float L1 = S[(size_t)i0 * CO1 + 64 + lane] * w0
                 + S[(size_t)i1 * CO1 + 64 + lane] * w1
                 + S[(size_t)i2 * CO1 + 64 + lane] * w2;

        float fv = featT[((size_t)b * NPTS + n) * CFEAT + lane];

        float a0 = 0.0f, a1 = 0.0f;
#pragma unroll
        for (int c = 0; c < 64; c++) {
            f32x2 w = w2t2[c][lane];
            float g = rlane(fv, c);
            a0 = fmaf(w.x, g, a0); a1 = fmaf(w.y, g, a1);
        }
#pragma unroll
        for (int c = 0; c < 64; c++) {
            f32x2 w = w2t2[64 + c][lane];
            float g = rlane(L0, c);
            a0 = fmaf(w.x, g, a0); a1 = fmaf(w.y, g, a1);
        }
#pragma unroll
        for (int c = 0; c < 64; c++) {
            f32x2 w = w2t2[128 + c][lane];
            float g = rlane(L1, c);
            a0 = fmaf(w.x, g, a0); a1 = fmaf(w.y, g, a1);
        }
        out[((size_t)b * CO2 + lane) * NPTS + n] = fmaxf(a0, 0.0f);
        out[((size_t)b * CO2 + 64 + lane) * NPTS + n] = fmaxf(a1, 0.0f);
    }
}

// ============================================================================
extern "C" void kernel_launch(void* const* d_in, const int* in_sizes, int n_in,
                              void* d_out, int out_size, void* d_ws, size_t ws_size,
                              hipStream_t stream) {
    const float* xyz      = (const float*)d_in[0];  // (4,8192,3)
    const float* features = (const float*)d_in[1];  // (4,64,8192)
    const float* W1       = (const float*)d_in[2];  // (128,67)
    const float* W2       = (const float*)d_in[3];  // (128,192)
    float* out = (float*)d_out;                     // (4,128,8192)

    float* featT   = (float*)d_ws;                          // 4*8192*64
    float* new_xyz = featT + (size_t)BATCH * NPTS * CFEAT;  // 4*2048*3
    int*   nidx    = (int*)(new_xyz + (size_t)BATCH * NSAMP * 3); // 4*2048*16
    float* subxT   = (float*)(nidx + (size_t)BATCH * NSAMP * NK); // 4*2048*128

    transpose_kernel<<<dim3(NPTS / 64, BATCH), 256, 0, stream>>>(features, featT);
    fps_kernel<<<BATCH, 1024, 0, stream>>>(xyz, new_xyz);
    ballq_kernel<<<(BATCH * NSAMP) / 4, 256, 0, stream>>>(xyz, new_xyz, nidx);
    group_mlp_kernel<<<512, 256, 0, stream>>>(xyz, featT, new_xyz, nidx, W1, subxT);
    interp_w2_kernel<<<256, 512, 0, stream>>>(xyz, new_xyz, featT, subxT, W2, out);
}

// Round 11
// 2482.964 us; speedup vs baseline: 1.2471x; 1.2471x over previous
//
#include <hip/hip_runtime.h>
#include <hip/hip_bf16.h>

// Sizes (fixed by the problem)
#define BATCH 4
#define NPTS  8192
#define NSAMP 2048
#define NK    16
#define CFEAT 64
#define CG    67      // 3 + 64
#define CO1   128
#define CCAT  192     // 64 + 128
#define CO2   128

#define DEV __device__ __forceinline__

typedef float f32x2 __attribute__((ext_vector_type(2)));

// --- exact-rounding helpers (block fp-contraction; match reference numerics) ---
DEV float n3(float x, float y, float z) {
    return __fadd_rn(__fadd_rn(__fmul_rn(x, x), __fmul_rn(y, y)), __fmul_rn(z, z));
}
DEV float dot3(float ax, float ay, float az, float bx, float by, float bz) {
    return __fmaf_rn(az, bz, __fmaf_rn(ay, by, __fmul_rn(ax, bx)));
}
DEV float sqd_expand(float an, float bn, float d) {
    return __fsub_rn(__fadd_rn(an, bn), __fmul_rn(2.0f, d));
}

// --- packed f32 ops (VOP3P): IEEE rn per element, identical to scalar VALU ---
DEV f32x2 pk_add(f32x2 a, f32x2 b) {
    f32x2 d;
    asm("v_pk_add_f32 %0, %1, %2" : "=v"(d) : "v"(a), "v"(b));
    return d;
}
DEV f32x2 pk_mul(f32x2 a, f32x2 b) {
    f32x2 d;
    asm("v_pk_mul_f32 %0, %1, %2" : "=v"(d) : "v"(a), "v"(b));
    return d;
}

// one DPP max step: x = max(x, lanes-moved(x)); invalid lanes keep x (old)
#define DPPMAX(x, ctrl)                                                        \
    x = fmaxf(x, __int_as_float(__builtin_amdgcn_update_dpp(                   \
            __float_as_int(x), __float_as_int(x), (ctrl), 0xF, 0xF, false)))

DEV float rlane(float v, int l) {   // readlane (uniform l) -> SGPR broadcast
    return __int_as_float(__builtin_amdgcn_readlane(__float_as_int(v), l));
}

// ============================================================================
// K0: transpose features (B,64,8192) -> featT (B,8192,64) for coalesced gathers
// ============================================================================
__global__ __launch_bounds__(256) void transpose_kernel(const float* __restrict__ F,
                                                        float* __restrict__ T) {
    __shared__ float tile[64][65];
    const int b = blockIdx.y;
    const int n0 = blockIdx.x * 64;
    const int tx = threadIdx.x & 63, ty = threadIdx.x >> 6; // ty: 0..3
    const float* Fb = F + (size_t)b * CFEAT * NPTS;
    float* Tb = T + (size_t)b * NPTS * CFEAT;
#pragma unroll
    for (int i = 0; i < 16; i++) {
        int c = ty + i * 4;
        tile[c][tx] = Fb[(size_t)c * NPTS + n0 + tx];
    }
    __syncthreads();
#pragma unroll
    for (int i = 0; i < 16; i++) {
        int r = ty + i * 4;
        Tb[(size_t)(n0 + r) * CFEAT + tx] = tile[tx][r];
    }
}

// ============================================================================
// K1: farthest point sampling — the measured-best R7 structure, verbatim.
// One block (512 thr = 8 waves) per batch; thread t owns contiguous points
// [16t,16t+16) in registers (f32x2-packed). Per iteration (ONE barrier):
//   update: packed v_pk (x + (-c) == x - c exactly; mul/add order matches
//     numpy) + scalar v_min per point.
//   per-lane argmax: fmax tree + descending == scan (lowest j).
//   wave max: 6-step f32 DPP -> readlane(63) -> ballot -> lowest lane.
//   lane0 writes packed u64 (bits(v)<<32 | ~idx) to wred[parity][wave].
//   barrier; ALL threads redundantly reduce 8 winners (same-addr LDS
//   broadcast reads) + fetch centroid. Parity double-buffer removes bar 2.
// u64 pack: v>=0 so f32 bits are order-monotone; max == max value with
// min-index tie-break == jnp.argmax first-occurrence (contiguous ownership:
// lowest lane/lowest j == lowest global index).
// ============================================================================
__global__ __launch_bounds__(512, 2) void fps_kernel(const float* __restrict__ xyz,
                                                     float* __restrict__ new_xyz) {
    const int b = blockIdx.x;
    const int t = threadIdx.x;              // 0..511
    const int lane = t & 63, wv = t >> 6;   // 8 waves
    const float* X = xyz + (size_t)b * NPTS * 3;

    __shared__ float sx[NPTS], sy[NPTS], sz[NPTS];      // 96 KiB
    __shared__ unsigned long long wred[2][8];

    f32x2 px[8], py[8], pz[8], dd[8];       // 16 pts as 8 pairs
    // load 16 points = 48 floats = 12 float4 per thread
    {
        const float4* X4 = (const float4*)X;
#pragma unroll
        for (int g = 0; g < 4; g++) {
            float4 f0 = X4[t * 12 + g * 3 + 0];
            float4 f1 = X4[t * 12 + g * 3 + 1];
            float4 f2 = X4[t * 12 + g * 3 + 2];
            px[2*g+0].x = f0.x; py[2*g+0].x = f0.y; pz[2*g+0].x = f0.z;
            px[2*g+0].y = f0.w; py[2*g+0].y = f1.x; pz[2*g+0].y = f1.y;
            px[2*g+1].x = f1.z; py[2*g+1].x = f1.w; pz[2*g+1].x = f2.x;
            px[2*g+1].y = f2.y; py[2*g+1].y = f2.z; pz[2*g+1].y = f2.w;
        }
#pragma unroll
        for (int j = 0; j < 8; j++) {
            int p = t * 16 + 2 * j;
            sx[p] = px[j].x; sy[p] = py[j].x; sz[p] = pz[j].x;
            sx[p + 1] = px[j].y; sy[p + 1] = py[j].y; sz[p + 1] = pz[j].y;
            dd[j].x = 1e10f; dd[j].y = 1e10f;
        }
    }
    __syncthreads();

    float cx = sx[0], cy = sy[0], cz = sz[0];   // first sampled index is 0
    if (t == 0) {
        size_t o = (size_t)b * NSAMP * 3;
        new_xyz[o + 0] = cx; new_xyz[o + 1] = cy; new_xyz[o + 2] = cz;
    }

    int par = 0;
    for (int s = 1; s < NSAMP; s++) {
        // ---- packed update: d = ((dx*dx + dy*dy) + dz*dz); x-c == x+(-c) ----
        const float ncx = -cx, ncy = -cy, ncz = -cz;
        const f32x2 vcx = {ncx, ncx}, vcy = {ncy, ncy}, vcz = {ncz, ncz};
#pragma unroll
        for (int j = 0; j < 8; j++) {
            f32x2 dx = pk_add(px[j], vcx);
            f32x2 dy = pk_add(py[j], vcy);
            f32x2 dz = pk_add(pz[j], vcz);
            f32x2 d = pk_add(pk_add(pk_mul(dx, dx), pk_mul(dy, dy)), pk_mul(dz, dz));
            dd[j].x = fminf(dd[j].x, d.x);
            dd[j].y = fminf(dd[j].y, d.y);
        }
        // ---- per-lane max (tree) ----
        float m[8];
#pragma unroll
        for (int j = 0; j < 8; j++) m[j] = fmaxf(dd[j].x, dd[j].y);
#pragma unroll
        for (int j = 0; j < 4; j++) m[j] = fmaxf(m[j], m[j + 4]);
        float bv = fmaxf(fmaxf(m[0], m[1]), fmaxf(m[2], m[3]));
        // lowest owned j with dist == bv (descending overwrite scan)
        int bj = 15;
#pragma unroll
        for (int j = 14; j >= 0; --j) {
            float dj = (j & 1) ? dd[j >> 1].y : dd[j >> 1].x;
            if (dj == bv) bj = j;
        }
        const int lidx = t * 16 + bj;

        // ---- wave max via DPP (VALU-speed, no LDS) ----
        float wm = bv;
        DPPMAX(wm, 0x111);   // row_shr:1
        DPPMAX(wm, 0x112);   // row_shr:2
        DPPMAX(wm, 0x114);   // row_shr:4
        DPPMAX(wm, 0x118);   // row_shr:8  -> lane15 of each row = row max
        DPPMAX(wm, 0x142);   // row_bcast:15
        DPPMAX(wm, 0x143);   // row_bcast:31 -> lane63 = wave max
        const float wmax = __int_as_float(
            __builtin_amdgcn_readlane(__float_as_int(wm), 63));
        const unsigned long long em = __ballot(bv == wmax);
        const int wl = (int)__builtin_ctzll(em);       // lowest lane = lowest idx
        const int widx = __builtin_amdgcn_readlane(lidx, wl);

        if (lane == 0)
            wred[par][wv] = ((unsigned long long)__float_as_uint(wmax) << 32)
                          | (unsigned int)(~widx);
        __syncthreads();                       // the ONLY barrier per iter

        // ---- redundant cross-wave reduce (8 winners, LDS broadcast) --------
        unsigned long long r0 = wred[par][0], r1 = wred[par][1];
        unsigned long long r2 = wred[par][2], r3 = wred[par][3];
        unsigned long long r4 = wred[par][4], r5 = wred[par][5];
        unsigned long long r6 = wred[par][6], r7 = wred[par][7];
        if (r1 > r0) r0 = r1;
        if (r3 > r2) r2 = r3;
        if (r5 > r4) r4 = r5;
        if (r7 > r6) r6 = r7;
        if (r2 > r0) r0 = r2;
        if (r6 > r4) r4 = r6;
        if (r4 > r0) r0 = r4;
        const int idx = (int)(~(unsigned int)(r0 & 0xFFFFFFFFull));

        cx = sx[idx]; cy = sy[idx]; cz = sz[idx];   // same-addr broadcast
        if (t == 0) {
            size_t o = ((size_t)b * NSAMP + s) * 3;
            new_xyz[o + 0] = cx; new_xyz[o + 1] = cy; new_xyz[o + 2] = cz;
        }
        par ^= 1;
    }
}

// ============================================================================
// K2: ball query. One wave per query; scan points in rounds of 64 in index
// order, collect first 16 within radius^2=0.04, pad with first. Early exit.
// ============================================================================
__global__ __launch_bounds__(256) void ballq_kernel(const float* __restrict__ xyz,
                                                    const float* __restrict__ new_xyz,
                                                    int* __restrict__ nidx) {
    const int wv = threadIdx.x >> 6, lane = threadIdx.x & 63;
    const int q = blockIdx.x * 4 + wv;          // 0..8191
    const int b = q >> 11;
    const float* X = xyz + (size_t)b * NPTS * 3;
    const float* Q = new_xyz + (size_t)q * 3;
    const float qx = Q[0], qy = Q[1], qz = Q[2];
    const float an = n3(qx, qy, qz);

    __shared__ int nb[4][NK];
    int cnt = 0;
    for (int base = 0; base < NPTS && cnt < NK; base += 64) {
        int p = base + lane;
        float x = X[p * 3 + 0], y = X[p * 3 + 1], z = X[p * 3 + 2];
        float bn = n3(x, y, z);
        float dt = dot3(qx, qy, qz, x, y, z);
        float sq = sqd_expand(an, bn, dt);
        bool in = (sq <= 0.04f);                // == (NOT sq > r^2)
        unsigned long long m = __ballot(in);
        if (in) {
            int pos = cnt + (int)__popcll(m & ((1ull << lane) - 1ull));
            if (pos < NK) nb[wv][pos] = p;
        }
        cnt += (int)__popcll(m);
    }
    __syncthreads();
    if (lane < NK) {
        int c = cnt < NK ? cnt : NK;
        int v = (lane < c) ? nb[wv][lane] : nb[wv][0];  // pad with first
        nidx[(size_t)q * NK + lane] = v;
    }
}

// ============================================================================
// K3: grouping + W1 (128x67) + relu + max over k -> subxT (B,2048,128)
// Paired weights in LDS (1 ds_read_b64 per d feeds both output halves),
// feature broadcast via readlane (VALU, no ds_bpermute), 2 neighbors
// interleaved -> 4 independent fma chains.
// ============================================================================
__global__ __launch_bounds__(256) void group_mlp_kernel(const float* __restrict__ xyz,
                                                        const float* __restrict__ featT,
                                                        const float* __restrict__ new_xyz,
                                                        const int* __restrict__ nidx,
                                                        const float* __restrict__ W1,
                                                        float* __restrict__ subxT) {
    __shared__ f32x2 w1t2[CG][64];   // 33.5 KiB: {W1[o][d], W1[o+64][d]}
    for (int i = threadIdx.x; i < CG * 64; i += 256) {
        int d = i >> 6, o = i & 63;
        w1t2[d][o].x = W1[(size_t)o * CG + d];
        w1t2[d][o].y = W1[(size_t)(o + 64) * CG + d];
    }
    __syncthreads();
    const int lane = threadIdx.x & 63, wv = threadIdx.x >> 6;

    for (int q = blockIdx.x * 4 + wv; q < BATCH * NSAMP; q += gridDim.x * 4) {
        const int b = q >> 11;
        const float* Q = new_xyz + (size_t)q * 3;
        const float qx = Q[0], qy = Q[1], qz = Q[2];
        const int* NB = nidx + (size_t)q * NK;
        float m0 = 0.0f, m1 = 0.0f;  // max(relu(h)) == max(0, max h)
#pragma unroll 1
        for (int k = 0; k < NK; k += 2) {
            const int n0 = NB[k], n1 = NB[k + 1];
            const float* P0 = xyz + ((size_t)b * NPTS + n0) * 3;
            const float* P1 = xyz + ((size_t)b * NPTS + n1) * 3;
            float rx0 = P0[0] - qx, ry0 = P0[1] - qy, rz0 = P0[2] - qz;
            float rx1 = P1[0] - qx, ry1 = P1[1] - qy, rz1 = P1[2] - qz;
            float fv0 = featT[((size_t)b * NPTS + n0) * CFEAT + lane];
            float fv1 = featT[((size_t)b * NPTS + n1) * CFEAT + lane];
            f32x2 w0 = w1t2[0][lane], w1 = w1t2[1][lane], w2 = w1t2[2][lane];
            float a0 = fmaf(w0.x, rx0, fmaf(w1.x, ry0, w2.x * rz0));
            float a1 = fmaf(w0.y, rx0, fmaf(w1.y, ry0, w2.y * rz0));
            float c0 = fmaf(w0.x, rx1, fmaf(w1.x, ry1, w2.x * rz1));
            float c1 = fmaf(w0.y, rx1, fmaf(w1.y, ry1, w2.y * rz1));
#pragma unroll
            for (int c = 0; c < 64; c++) {
                f32x2 w = w1t2[3 + c][lane];
                float g0 = rlane(fv0, c);
                float g1 = rlane(fv1, c);
                a0 = fmaf(w.x, g0, a0);
                a1 = fmaf(w.y, g0, a1);
                c0 = fmaf(w.x, g1, c0);
                c1 = fmaf(w.y, g1, c1);
            }
            m0 = fmaxf(m0, fmaxf(a0, c0));
            m1 = fmaxf(m1, fmaxf(a1, c1));
        }
        subxT[(size_t)q * CO1 + lane] = m0;
        subxT[(size_t)q * CO1 + 64 + lane] = m1;
    }
}

// ============================================================================
// K4: 3-NN interpolation + concat + W2 (128x192) + relu -> out (B,128,8192)
// One wave per output point. Top-3 via per-lane sorted insert + butterfly merge
// with (d, idx) lexicographic compare (== lax.top_k stability). Matvec with
// paired weights (1 ds_read_b64 per d) + readlane broadcast of the per-lane
// cat values (fv/L0/L1) -> no catb LDS round-trip.
// ============================================================================
DEV void ins3(float dd, int jj,
              float& d0, int& i0, float& d1, int& i1, float& d2, int& i2) {
    bool c2 = (dd < d2) || (dd == d2 && jj < i2);
    if (c2) { d2 = dd; i2 = jj; }
    bool c1 = (d2 < d1) || (d2 == d1 && i2 < i1);
    if (c1) { float tv = d1; int ti = i1; d1 = d2; i1 = i2; d2 = tv; i2 = ti; }
    bool c0 = (d1 < d0) || (d1 == d0 && i1 < i0);
    if (c0) { float tv = d0; int ti = i0; d0 = d1; i0 = i1; d1 = tv; i1 = ti; }
}

__global__ __launch_bounds__(256) void interp_w2_kernel(const float* __restrict__ xyz,
                                                        const float* __restrict__ new_xyz,
                                                        const float* __restrict__ featT,
                                                        const float* __restrict__ subxT,
                                                        const float* __restrict__ W2,
                                                        float* __restrict__ out) {
    __shared__ f32x2 w2t2[CCAT][64];  // 96 KiB: {W2[o][d], W2[o+64][d]}
    for (int i = threadIdx.x; i < CCAT * 64; i += 256) {
        int d = i >> 6, o = i & 63;
        w2t2[d][o].x = W2[(size_t)o * CCAT + d];
        w2t2[d][o].y = W2[(size_t)(o + 64) * CCAT + d];
    }
    __syncthreads();
    const int lane = threadIdx.x & 63, wv = threadIdx.x >> 6;

    for (int q = blockIdx.x * 4 + wv; q < BATCH * NPTS; q += gridDim.x * 4) {
        const int b = q >> 13, n = q & (NPTS - 1);
        const float* P = xyz + (size_t)q * 3;
        const float qx = P[0], qy = P[1], qz = P[2];
        const float an = n3(qx, qy, qz);

        float d0 = 1e30f, d1 = 1e30f, d2 = 1e30f;
        int i0 = 0x7fffffff, i1 = 0x7fffffff, i2 = 0x7fffffff;
        for (int j = lane; j < NSAMP; j += 64) {
            const float* C = new_xyz + ((size_t)b * NSAMP + j) * 3;
            float x = C[0], y = C[1], z = C[2];
            float bn = n3(x, y, z);
            float dt = dot3(qx, qy, qz, x, y, z);
            float dd = sqd_expand(an, bn, dt);
            ins3(dd, j, d0, i0, d1, i1, d2, i2);
        }
#pragma unroll
        for (int off = 32; off > 0; off >>= 1) {
            float e0 = __shfl_xor(d0, off); int f0 = __shfl_xor(i0, off);
            float e1 = __shfl_xor(d1, off); int f1 = __shfl_xor(i1, off);
            float e2 = __shfl_xor(d2, off); int f2 = __shfl_xor(i2, off);
            ins3(e0, f0, d0, i0, d1, i1, d2, i2);
            ins3(e1, f1, d0, i0, d1, i1, d2, i2);
            ins3(e2, f2, d0, i0, d1, i1, d2, i2);
        }
        float w0 = 1.0f / (d0 + 1e-8f);
        float w1 = 1.0f / (d1 + 1e-8f);
        float w2 = 1.0f / (d2 + 1e-8f);
        float sw = (w0 + w1) + w2;
        w0 /= sw; w1 /= sw; w2 /= sw;

        // lerp channels c=lane and c=lane+64 (coalesced row gathers)
        const float* S = subxT + (size_t)b * NSAMP * CO1;
        float L0 = S[(size_t)i0 * CO1 + lane] * w0
                 + S[(size_t)i1 * CO1 + lane] * w1
                 + S[(size_t)i2 * CO1 + lane] * w2;
        float L1 = S[(size_t)i0 * CO1 + 64 + lane] * w0
                 + S[(size_t)i1 * CO1 + 64 + lane] * w1
                 + S[(size_t)i2 * CO1 + 64 + lane] * w2;

        float fv = featT[((size_t)b * NPTS + n) * CFEAT + lane];

        float a0 = 0.0f, a1 = 0.0f;
#pragma unroll
        for (int c = 0; c < 64; c++) {          // cat[0:64] = features
            f32x2 w = w2t2[c][lane];
            float g = rlane(fv, c);
            a0 = fmaf(w.x, g, a0); a1 = fmaf(w.y, g, a1);
        }
#pragma unroll
        for (int c = 0; c < 64; c++) {          // cat[64:128] = lerp lo
            f32x2 w = w2t2[64 + c][lane];
            float g = rlane(L0, c);
            a0 = fmaf(w.x, g, a0); a1 = fmaf(w.y, g, a1);
        }
#pragma unroll
        for (int c = 0; c < 64; c++) {          // cat[128:192] = lerp hi
            f32x2 w = w2t2[128 + c][lane];
            float g = rlane(L1, c);
            a0 = fmaf(w.x, g, a0); a1 = fmaf(w.y, g, a1);
        }
        out[((size_t)b * CO2 + lane) * NPTS + n] = fmaxf(a0, 0.0f);
        out[((size_t)b * CO2 + 64 + lane) * NPTS + n] = fmaxf(a1, 0.0f);
    }
}

// ============================================================================
extern "C" void kernel_launch(void* const* d_in, const int* in_sizes, int n_in,
                              void* d_out, int out_size, void* d_ws, size_t ws_size,
                              hipStream_t stream) {
    const float* xyz      = (const float*)d_in[0];  // (4,8192,3)
    const float* features = (const float*)d_in[1];  // (4,64,8192)
    const float* W1       = (const float*)d_in[2];  // (128,67)
    const float* W2       = (const float*)d_in[3];  // (128,192)
    float* out = (float*)d_out;                     // (4,128,8192)

    // workspace layout (floats/ints), total ~12.6 MB
    float* featT   = (float*)d_ws;                          // 4*8192*64
    float* new_xyz = featT + (size_t)BATCH * NPTS * CFEAT;  // 4*2048*3
    int*   nidx    = (int*)(new_xyz + (size_t)BATCH * NSAMP * 3); // 4*2048*16
    float* subxT   = (float*)(nidx + (size_t)BATCH * NSAMP * NK); // 4*2048*128

    transpose_kernel<<<dim3(NPTS / 64, BATCH), 256, 0, stream>>>(features, featT);
    fps_kernel<<<BATCH, 512, 0, stream>>>(xyz, new_xyz);
    ballq_kernel<<<(BATCH * NSAMP) / 4, 256, 0, stream>>>(xyz, new_xyz, nidx);
    group_mlp_kernel<<<512, 256, 0, stream>>>(xyz, featT, new_xyz, nidx, W1, subxT);
    interp_w2_kernel<<<256, 256, 0, stream>>>(xyz, new_xyz, featT, subxT, W2, out);
}